// Round 8
// baseline (559.059 us; speedup 1.0000x reference)
//
#include <hip/hip_runtime.h>
#include <math.h>

// ---------------------------------------------------------------------------
// LinearNO block, MI355X/gfx950. Inputs fp32 (sniffed; bf16 fallback).
// Interior bf16 MFMA. B=8 N=8192 C=256 H=8 D=32 S=32.
//
// R15 changes vs R14 (485 us):
//  * steps 4+5+6 (Qs gemm, qkv gemm, Wo gemm ~105 us) fused into ONE kernel
//    qkvwo: Wq shared [32x32] + block-diag KV + Wo slices are tiny LDS
//    tables; per head: QL (4 MFMA) -> in-reg segsoftmax (act=3 code) ->
//    per-wave t-exchange -> qkv (4 MFMA) -> t-exchange -> Wo-accum
//    (32 MFMA, 16KB slice dbuf staged per head). Qs/qkv2d never hit HBM
//    (-128 MB, -2 launches).
//  * step 2 (E2d gemm ~35 us) fused into accumG: E recomputed in-register
//    (wk row per thread; reuses the same Xl reads; Xl reads are 2-address
//    broadcasts). E2d never materialized (-64 MB).
//  * kv_build emits compact kvT[b][h][d][s]; Wqbig/Wkbig/build_big/zero_u16
//    and gemm_bt deleted. fused_mlp = R14 proven version, unchanged.
// ---------------------------------------------------------------------------

typedef __attribute__((ext_vector_type(8))) short bf8;
typedef __attribute__((ext_vector_type(4))) float f32x4;
typedef __attribute__((ext_vector_type(4))) unsigned short u16x4;
typedef __attribute__((ext_vector_type(8))) unsigned short u16x8;

__device__ __forceinline__ float b2f(unsigned short x) {
  union { unsigned u; float f; } t; t.u = ((unsigned)x) << 16; return t.f;
}
__device__ __forceinline__ unsigned short f2b(float f) {
  union { float f; unsigned u; } t; t.f = f;
  unsigned r = t.u + 0x7fffu + ((t.u >> 16) & 1u);
  return (unsigned short)(r >> 16);
}
__device__ __forceinline__ float gelu_exact(float x) {
  return 0.5f * x * (1.0f + erff(x * 0.7071067811865475f));
}
// A&S 7.1.26 erf, |eps| <= 1.5e-7 (abs).
__device__ __forceinline__ float erf_fast(float x) {
  float ax = fabsf(x);
  float t = __builtin_amdgcn_rcpf(fmaf(0.3275911f, ax, 1.0f));
  float p = t * fmaf(t, fmaf(t, fmaf(t, fmaf(t, 1.061405429f, -1.453152027f),
                                     1.421413741f), -0.284496736f), 0.254829592f);
  float r = 1.0f - p * __expf(-ax * ax);
  return copysignf(r, x);
}
__device__ __forceinline__ float gelu_fast(float x) {
  return 0.5f * x * (1.0f + erf_fast(x * 0.7071067811865475f));
}

// async global->LDS, 16 B per lane. LDS dest must be base + lane*16.
typedef __attribute__((address_space(1))) const void gas_void;
typedef __attribute__((address_space(3))) void las_void;
__device__ __forceinline__ void gl_lds16(const void* g, void* l) {
  __builtin_amdgcn_global_load_lds((gas_void*)g, (las_void*)l, 16, 0, 0);
}

// --------------------------- dtype sniffer ---------------------------------
__global__ void sniff_kernel(const unsigned* __restrict__ fx, int* __restrict__ flag,
                             unsigned* __restrict__ gate) {
  if (threadIdx.x == 0) {
    int cnt = 0;
    for (int i = 0; i < 64; i++) {
      unsigned e = (fx[i] >> 7) & 0xFFu;
      cnt += (e >= 117u && e <= 130u) ? 1 : 0;
    }
    *flag = (cnt >= 32) ? 1 : 0;   // 1 = bf16 inputs, 0 = fp32
    *gate = 0u;                    // MLP ordering gate (re-zeroed every replay)
  }
}

// --------------------------- weight table ----------------------------------
struct CvtDesc { const void* src[15]; int off[15]; int n[15]; };

__global__ __launch_bounds__(256) void cvt_tab(CvtDesc d, unsigned short* __restrict__ wtab,
                                               const int* __restrict__ flagp) {
  const int seg = blockIdx.y;
  const int i = blockIdx.x * 256 + threadIdx.x;
  if (i >= d.n[seg]) return;
  unsigned short o;
  if (*flagp) o = ((const unsigned short*)d.src[seg])[i];
  else        o = f2b(((const float*)d.src[seg])[i]);
  wtab[d.off[seg] + i] = o;
}

// --------------------------- LN stats --------------------------------------
__global__ __launch_bounds__(256) void ln_stats(
    const void* __restrict__ X, const int* __restrict__ flagp, int amode,
    float* __restrict__ MU, float* __restrict__ RS)
{
  const int lane = threadIdx.x & 63;
  const int wave = threadIdx.x >> 6;
  const size_t row = (size_t)blockIdx.x * 4 + wave;
  const size_t base = row * 256 + lane * 4;
  const bool abf = amode ? ((*flagp) != 0) : true;
  float x0, x1, x2, x3;
  if (abf) {
    u16x4 uv = *(const u16x4*)&((const unsigned short*)X)[base];
    x0 = b2f(uv[0]); x1 = b2f(uv[1]); x2 = b2f(uv[2]); x3 = b2f(uv[3]);
  } else {
    f32x4 t = *(const f32x4*)&((const float*)X)[base];
    x0 = t[0]; x1 = t[1]; x2 = t[2]; x3 = t[3];
  }
  float s = x0 + x1 + x2 + x3;
  float q = x0*x0 + x1*x1 + x2*x2 + x3*x3;
  #pragma unroll
  for (int m = 1; m < 64; m <<= 1) { s += __shfl_xor(s, m, 64); q += __shfl_xor(q, m, 64); }
  float mean = s * (1.0f / 256.0f);
  float var  = q * (1.0f / 256.0f) - mean * mean;
  if (lane == 0) { MU[row] = mean; RS[row] = rsqrtf(var + 1e-5f); }
}

// GEMM with LN applied to A during staging (amode: 1=flag dtype, 0=bf16);
// B side uses DMA staging. Coalesced LDS epilogue. (step 1 only)
__global__ __launch_bounds__(256) void gemm_bt_ln(
    const void* __restrict__ A, const int* __restrict__ flagp, int amode,
    const float* __restrict__ MU, const float* __restrict__ RS,
    const unsigned short* __restrict__ lw, const unsigned short* __restrict__ lb,
    const unsigned short* __restrict__ W, const unsigned short* __restrict__ bias,
    unsigned short* __restrict__ Y, int N, int K, int act)
{
  __shared__ __align__(16) unsigned char smemc[32768];       // lA+lB, cf overlay
  unsigned short* lA = (unsigned short*)smemc;
  unsigned short* lB = lA + 4096;
  const int tid = threadIdx.x, lane = tid & 63, wave = tid >> 6;
  const int bm = blockIdx.x * 128, bn = blockIdx.y * 128;
  const int wm = (wave >> 1) * 64, wn = (wave & 1) * 64;
  const int quad = lane >> 4, l16 = lane & 15;
  const bool abf = amode ? ((*flagp) != 0) : true;
  const unsigned short* Ab = (const unsigned short*)A;
  const float* Af = (const float*)A;

  f32x4 acc[4][4] = {};
  const int r0 = tid >> 2;
  const int co = (tid & 3) * 8;
  const unsigned short* pb0 = &W[(size_t)(bn + r0) * K + co];
  const unsigned short* pb1 = &W[(size_t)(bn + r0 + 64) * K + co];

  for (int k0 = 0; k0 < K; k0 += 32) {
    u16x8 wv8 = *(const u16x8*)&lw[k0 + co];
    u16x8 bv8 = *(const u16x8*)&lb[k0 + co];
    __syncthreads();
    gl_lds16(pb0 + k0, &lB[tid * 8]);
    gl_lds16(pb1 + k0, &lB[2048 + tid * 8]);
    #pragma unroll
    for (int half = 0; half < 2; half++) {
      const int ar = bm + r0 + half * 64;
      const float m_ = MU[ar], r_ = RS[ar];
      float xv[8];
      if (abf) {
        u16x8 t = *(const u16x8*)&Ab[(size_t)ar * K + k0 + co];
        #pragma unroll
        for (int e = 0; e < 8; e++) xv[e] = b2f(t[e]);
      } else {
        f32x4 t0 = *(const f32x4*)&Af[(size_t)ar * K + k0 + co];
        f32x4 t1 = *(const f32x4*)&Af[(size_t)ar * K + k0 + co + 4];
        xv[0]=t0[0]; xv[1]=t0[1]; xv[2]=t0[2]; xv[3]=t0[3];
        xv[4]=t1[0]; xv[5]=t1[1]; xv[6]=t1[2]; xv[7]=t1[3];
      }
      u16x8 o;
      #pragma unroll
      for (int e = 0; e < 8; e++)
        o[e] = f2b((xv[e] - m_) * r_ * b2f(wv8[e]) + b2f(bv8[e]));
      *(u16x8*)&lA[half * 2048 + tid * 8] = o;
    }
    __syncthreads();

    bf8 af[4], bfr[4];
    #pragma unroll
    for (int i = 0; i < 4; i++) af[i]  = *(const bf8*)&lA[(wm + i * 16 + l16) * 32 + quad * 8];
    #pragma unroll
    for (int j = 0; j < 4; j++) bfr[j] = *(const bf8*)&lB[(wn + j * 16 + l16) * 32 + quad * 8];
    #pragma unroll
    for (int i = 0; i < 4; i++)
      #pragma unroll
      for (int j = 0; j < 4; j++)
        acc[i][j] = __builtin_amdgcn_mfma_f32_16x16x32_bf16(af[i], bfr[j], acc[i][j], 0, 0, 0);
  }

  float bv[4];
  #pragma unroll
  for (int j = 0; j < 4; j++) bv[j] = b2f(bias[bn + wn + j * 16 + l16]);
  #pragma unroll
  for (int i = 0; i < 4; i++)
    #pragma unroll
    for (int j = 0; j < 4; j++)
      #pragma unroll
      for (int r = 0; r < 4; r++) {
        float v = acc[i][j][r] + bv[j];
        if (act) v = gelu_exact(v);
        acc[i][j][r] = v;
      }

  float* cf = (float*)smemc;
  const int whalf = wm >> 6;
  #pragma unroll
  for (int half = 0; half < 2; ++half) {
    __syncthreads();
    if (whalf == half) {
      #pragma unroll
      for (int i = 0; i < 4; i++)
        #pragma unroll
        for (int j = 0; j < 4; j++)
          #pragma unroll
          for (int r = 0; r < 4; r++)
            cf[(i * 16 + quad * 4 + r) * 128 + wn + j * 16 + l16] = acc[i][j][r];
    }
    __syncthreads();
    #pragma unroll
    for (int st = 0; st < 4; ++st) {
      const int e = st * 2048 + tid * 8;
      const int row = e >> 7;
      const size_t gbase = (size_t)(bm + half * 64 + row) * N + bn + (e & 127);
      u16x8 o;
      #pragma unroll
      for (int u = 0; u < 8; u++) o[u] = f2b(cf[e + u]);
      *(u16x8*)&Y[gbase] = o;
    }
  }
}

// ---------------------------------------------------------------------------
// qkvwo: fused steps 4+5+6. Per 128-row block (within one batch b):
//   per head h: QL = xmid@Wq^T (K-slice h, 4 MFMA) -> segment softmax in regs
//   -> Ps via per-wave t-exchange -> qkv = Ps@kvT_h (4 MFMA) -> t-exchange
//   -> acc += qkv@Wo[:,h-slice]^T (32 MFMA, 16KB slice, 2-slot dbuf).
// Epilogue: h = acc + bo + fx -> xup (bf16). 4 waves, wave w rows w*32..+32,
// acc[2][16] f32x4, areg = xmid frags (loaded once, no LN).
// LDS: wq 4K @0 | kvT 16K @4096 | Wo dbuf 32K @20480 | t 4x5120 @53248
//  = 73728 B; cf epilogue [64][260] f32 overlays @0. 2 blocks/CU.
// All LDS tables staged with linear gl_lds16 dest + XOR-permuted source,
// read with the matching XOR (fused_mlp stageW2 pattern) -> <=2-way banks.
// ---------------------------------------------------------------------------
__global__ __launch_bounds__(256, 2) void qkvwo(
    const unsigned short* __restrict__ Xm,    // xmid [65536,256] bf16
    const unsigned short* __restrict__ wq,    // [32 s][32 d]
    const unsigned short* __restrict__ kvTg,  // [8 b][8 h][32 d][32 s]
    const unsigned short* __restrict__ Wo,    // [256][256]
    const unsigned short* __restrict__ bo,    // [256]
    const void* __restrict__ Fx, const int* __restrict__ flagp,
    unsigned short* __restrict__ Hout)
{
  __shared__ __align__(16) unsigned char smem[73728];
  const int tid = threadIdx.x, lane = tid & 63, wave = tid >> 6;
  const int quad = lane >> 4, l16 = lane & 15;
  const int brow = blockIdx.x * 128;
  const int b = brow >> 13;

  // ---- stage wq [32 rows x 32] (tid<128, 1 unit each)
  if (tid < 128) {
    const int row = tid >> 2, u = tid & 3;
    gl_lds16(wq + row * 32 + ((u ^ ((row >> 1) & 3)) * 8), smem + tid * 16);
  }
  // ---- stage kvT [256 rows x 32] (4 units/thread)
  {
    const unsigned short* src = kvTg + (size_t)b * 8192;
    #pragma unroll
    for (int s = 0; s < 4; s++) {
      const int unit = s * 256 + tid;
      const int row = unit >> 2, u = unit & 3;
      gl_lds16(src + row * 32 + ((u ^ ((row >> 1) & 3)) * 8), smem + 4096 + unit * 16);
    }
  }
  auto stageWo = [&](int hh, int slot) {
    const unsigned short* src = Wo + hh * 32;            // [256 rows][32 of 256]
    unsigned char* dst = smem + 20480 + slot * 16384;
    #pragma unroll
    for (int s = 0; s < 4; s++) {
      const int unit = s * 256 + tid;
      const int row = unit >> 2, u = unit & 3;
      gl_lds16(src + row * 256 + ((u ^ ((row >> 1) & 3)) * 8), dst + unit * 16);
    }
  };
  stageWo(0, 0);

  // ---- xmid A-fragments in registers (no LN): lane(q,l16), rg:
  //      row w*32+rg*16+l16, cols ks*32 + q*8 .. +7.
  bf8 areg[2][8];
  #pragma unroll
  for (int rg = 0; rg < 2; rg++) {
    const int myrow = wave * 32 + rg * 16 + l16;
    const unsigned short* hr = Xm + (size_t)(brow + myrow) * 256 + quad * 8;
    #pragma unroll
    for (int ks = 0; ks < 8; ks++)
      *(u16x8*)&areg[rg][ks] = *(const u16x8*)&hr[ks * 32];
  }

  asm volatile("s_waitcnt vmcnt(0) lgkmcnt(0)" ::: "memory");
  __builtin_amdgcn_s_barrier();
  __builtin_amdgcn_sched_barrier(0);

  f32x4 acc[2][16] = {};
  unsigned short* tw1 = (unsigned short*)(smem + 53248 + wave * 5120);
  unsigned short* tw2 = tw1 + 1280;
  const unsigned short* wql = (const unsigned short*)smem;
  const unsigned short* kvl = (const unsigned short*)(smem + 4096);

  #pragma unroll
  for (int h = 0; h < 8; ++h) {
    if (h < 7) stageWo(h + 1, (h + 1) & 1);

    // ---- QL: p[rg][jl] = xmid(k-slice h) @ wq^T  (C: row=n, col=s)
    f32x4 p[2][2] = {{{}, {}}, {{}, {}}};
    #pragma unroll
    for (int jl = 0; jl < 2; jl++) {
      const int row = jl * 16 + l16;
      bf8 wqf;
      *(u16x8*)&wqf = *(const u16x8*)&wql[row * 32 + ((quad ^ ((row >> 1) & 3)) * 8)];
      p[0][jl] = __builtin_amdgcn_mfma_f32_16x16x32_bf16(areg[0][h], wqf, p[0][jl], 0, 0, 0);
      p[1][jl] = __builtin_amdgcn_mfma_f32_16x16x32_bf16(areg[1][h], wqf, p[1][jl], 0, 0, 0);
    }

    // ---- segment softmax over the 32 s-cols (per row), then Ps -> tw1
    #pragma unroll
    for (int rg = 0; rg < 2; rg++)
      #pragma unroll
      for (int r = 0; r < 4; r++) {
        float a0 = p[rg][0][r], a1 = p[rg][1][r];
        float m = fmaxf(a0, a1);
        #pragma unroll
        for (int msk = 1; msk < 16; msk <<= 1) m = fmaxf(m, __shfl_xor(m, msk, 64));
        float e0 = __expf(a0 - m), e1 = __expf(a1 - m);
        float s = e0 + e1;
        #pragma unroll
        for (int msk = 1; msk < 16; msk <<= 1) s += __shfl_xor(s, msk, 64);
        const float rz = 1.0f / s;
        const int row = rg * 16 + quad * 4 + r;
        tw1[row * 40 + l16]      = f2b(e0 * rz);
        tw1[row * 40 + 16 + l16] = f2b(e1 * rz);
      }
    asm volatile("s_waitcnt lgkmcnt(0)" ::: "memory");
    __builtin_amdgcn_sched_barrier(0);

    // ---- qkv: p2[rg][jd] = Ps @ kvT_h^T  (A from tw1, B from kvl)
    bf8 ta0, ta1;
    *(u16x8*)&ta0 = *(const u16x8*)&tw1[l16 * 40 + quad * 8];
    *(u16x8*)&ta1 = *(const u16x8*)&tw1[(16 + l16) * 40 + quad * 8];
    asm volatile("s_waitcnt lgkmcnt(0)" ::: "memory");
    __builtin_amdgcn_sched_barrier(0);
    f32x4 p2[2][2] = {{{}, {}}, {{}, {}}};
    #pragma unroll
    for (int jd = 0; jd < 2; jd++) {
      const int row = h * 32 + jd * 16 + l16;
      bf8 kvf;
      *(u16x8*)&kvf = *(const u16x8*)&kvl[row * 32 + ((quad ^ ((row >> 1) & 3)) * 8)];
      p2[0][jd] = __builtin_amdgcn_mfma_f32_16x16x32_bf16(ta0, kvf, p2[0][jd], 0, 0, 0);
      p2[1][jd] = __builtin_amdgcn_mfma_f32_16x16x32_bf16(ta1, kvf, p2[1][jd], 0, 0, 0);
    }

    // ---- qkv C-layout -> tw2 (A-frags for Wo)
    #pragma unroll
    for (int rg = 0; rg < 2; rg++)
      #pragma unroll
      for (int jd = 0; jd < 2; jd++)
        #pragma unroll
        for (int r = 0; r < 4; r++)
          tw2[(rg * 16 + quad * 4 + r) * 40 + jd * 16 + l16] = f2b(p2[rg][jd][r]);
    asm volatile("s_waitcnt lgkmcnt(0)" ::: "memory");
    __builtin_amdgcn_sched_barrier(0);

    bf8 a20, a21;
    *(u16x8*)&a20 = *(const u16x8*)&tw2[l16 * 40 + quad * 8];
    *(u16x8*)&a21 = *(const u16x8*)&tw2[(16 + l16) * 40 + quad * 8];
    asm volatile("s_waitcnt lgkmcnt(0)" ::: "memory");
    __builtin_amdgcn_sched_barrier(0);

    // ---- Wo accumulation: acc[rg][j] += qkv_h @ Wo[:,h*32..+32)^T
    const unsigned short* wol = (const unsigned short*)(smem + 20480 + (h & 1) * 16384);
    #pragma unroll
    for (int j = 0; j < 16; j++) {
      const int row = j * 16 + l16;
      bf8 bw;
      *(u16x8*)&bw = *(const u16x8*)&wol[row * 32 + ((quad ^ ((row >> 1) & 3)) * 8)];
      acc[0][j] = __builtin_amdgcn_mfma_f32_16x16x32_bf16(a20, bw, acc[0][j], 0, 0, 0);
      acc[1][j] = __builtin_amdgcn_mfma_f32_16x16x32_bf16(a21, bw, acc[1][j], 0, 0, 0);
    }

    asm volatile("s_waitcnt vmcnt(0)" ::: "memory");   // Wo(h+1) staged (mine)
    __builtin_amdgcn_s_barrier();                      // all reads of slot done
    __builtin_amdgcn_sched_barrier(0);
  }

  // ---- epilogue: h = acc + bo + fx -> Hout, via cf [64][260] f32 overlay
  const bool rbf = (*flagp) != 0;
  float* cf = (float*)smem;
  #pragma unroll
  for (int hh = 0; hh < 2; ++hh) {
    __syncthreads();
    if ((wave >> 1) == hh) {
      const int wl = (wave & 1) * 32;
      #pragma unroll
      for (int rg = 0; rg < 2; rg++)
        #pragma unroll
        for (int j = 0; j < 16; j++)
          #pragma unroll
          for (int r = 0; r < 4; r++)
            cf[(wl + rg * 16 + quad * 4 + r) * 260 + j * 16 + l16] = acc[rg][j][r];
    }
    __syncthreads();
    #pragma unroll
    for (int s = 0; s < 8; s++) {
      const int e = s * 2048 + tid * 8;
      const int row = e >> 8, col = e & 255;
      const size_t gbase = (size_t)(brow + hh * 64 + row) * 256 + col;
      u16x8 bv = *(const u16x8*)&bo[col];
      float v[8];
      #pragma unroll
      for (int u = 0; u < 8; u++) v[u] = cf[row * 260 + col + u] + b2f(bv[u]);
      if (rbf) {
        u16x8 rv = *(const u16x8*)&((const unsigned short*)Fx)[gbase];
        #pragma unroll
        for (int u = 0; u < 8; u++) v[u] += b2f(rv[u]);
      } else {
        f32x4 ra = *(const f32x4*)&((const float*)Fx)[gbase];
        f32x4 rb = *(const f32x4*)&((const float*)Fx)[gbase + 4];
        v[0] += ra[0]; v[1] += ra[1]; v[2] += ra[2]; v[3] += ra[3];
        v[4] += rb[0]; v[5] += rb[1]; v[6] += rb[2]; v[7] += rb[3];
      }
      u16x8 o;
      #pragma unroll
      for (int u = 0; u < 8; u++) o[u] = f2b(v[u]);
      *(u16x8*)&Hout[gbase] = o;
    }
  }
}

// ---------------------------------------------------------------------------
// fused_mlp v5 (R14, proven): see R14 notes. Unchanged.
// ---------------------------------------------------------------------------
__global__ __launch_bounds__(512, 2) void fused_mlp(
    const unsigned short* __restrict__ Hlo,
    const unsigned short* __restrict__ Hhi,
    const float* __restrict__ MU, const float* __restrict__ RS,
    const unsigned short* __restrict__ lw, const unsigned short* __restrict__ lb,
    const unsigned short* __restrict__ W1, const unsigned short* __restrict__ bs1,
    const unsigned short* __restrict__ W2, const unsigned short* __restrict__ bs2,
    void* __restrict__ OUT, const int* __restrict__ flagp,
    unsigned* __restrict__ gate)
{
  __shared__ __align__(16) unsigned char smem[104448];
  const int tid = threadIdx.x, lane = tid & 63, wave = tid >> 6;
  const int quad = lane >> 4, l16 = lane & 15;
  const int bid = blockIdx.x;
  const bool low = (bid & 1) == 0;
  const long grow = (low ? 0L : 32768L) + (long)(bid >> 1) * 256;
  const unsigned short* hbase = low ? (Hlo + (size_t)grow * 256)
                                    : (Hhi + ((size_t)grow - 32768) * 256);

  auto stageW1 = [&](int c, int sl) {
    const unsigned short* src = W1 + (size_t)c * 8192;
    unsigned char* dst = smem + sl * 16384;
    #pragma unroll
    for (int s = 0; s < 2; s++) {
      const int unit = s * 512 + tid;
      const int row = unit >> 5, u = unit & 31;
      gl_lds16(src + row * 256 + ((u ^ (row & 7)) * 8), dst + unit * 16);
    }
  };
  auto stageW2 = [&](int c, int sl) {
    const unsigned short* src = W2 + c * 32;
    unsigned char* dst = smem + 49152 + sl * 16384;
    #pragma unroll
    for (int s = 0; s < 2; s++) {
      const int unit = s * 512 + tid;
      const int row = unit >> 2, u = unit & 3;
      gl_lds16(src + (size_t)row * 1024 + ((u ^ ((row >> 1) & 3)) * 8), dst + unit * 16);
    }
  };

  unsigned short* b1l = (unsigned short*)(smem + 102400);
  if (tid < 128) *(u16x8*)&b1l[tid * 8] = *(const u16x8*)&bs1[tid * 8];

  bf8 areg[2][8];
  #pragma unroll
  for (int rg = 0; rg < 2; rg++) {
    const int myrow = wave * 32 + rg * 16 + l16;
    const float m_ = MU[grow + myrow], r_ = RS[grow + myrow];
    const unsigned short* hr = hbase + (size_t)myrow * 256 + quad * 8;
    #pragma unroll
    for (int ks = 0; ks < 8; ks++) {
      u16x8 hv = *(const u16x8*)&hr[ks * 32];
      u16x8 wv = *(const u16x8*)&lw[ks * 32 + quad * 8];
      u16x8 bv = *(const u16x8*)&lb[ks * 32 + quad * 8];
      u16x8 o;
      #pragma unroll
      for (int e = 0; e < 8; e++)
        o[e] = f2b((b2f(hv[e]) - m_) * r_ * b2f(wv[e]) + b2f(bv[e]));
      *(u16x8*)&areg[rg][ks] = o;
    }
  }
  asm volatile("s_waitcnt vmcnt(0) lgkmcnt(0)" ::: "memory");

  stageW1(0, 0); stageW2(0, 0);
  stageW1(1, 1); stageW2(1, 1);
  asm volatile("s_waitcnt vmcnt(4)" ::: "memory");
  __builtin_amdgcn_s_barrier();
  __builtin_amdgcn_sched_barrier(0);

  f32x4 p00 = {}, p01 = {}, p10 = {}, p11 = {};
  {
    const unsigned short* w1b = (const unsigned short*)smem;
    #pragma unroll
    for (int ks = 0; ks < 8; ks++) {
      const int slot = (ks * 4 + quad) ^ (l16 & 7);
      bf8 a0, a1;
      *(u16x8*)&a0 = *(const u16x8*)&w1b[l16 * 256 + slot * 8];
      *(u16x8*)&a1 = *(const u16x8*)&w1b[(16 + l16) * 256 + slot * 8];
      p00 = __builtin_amdgcn_mfma_f32_16x16x32_bf16(a0, areg[0][ks], p00, 0, 0, 0);
      p01 = __builtin_amdgcn_mfma_f32_16x16x32_bf16(a0, areg[1][ks], p01, 0, 0, 0);
      p10 = __builtin_amdgcn_mfma_f32_16x16x32_bf16(a1, areg[0][ks], p10, 0, 0, 0);
      p11 = __builtin_amdgcn_mfma_f32_16x16x32_bf16(a1, areg[1][ks], p11, 0, 0, 0);
    }
  }

  f32x4 acc[2][16] = {};
  unsigned short* tw = (unsigned short*)(smem + 81920 + wave * 2560);
  const int gsw = (l16 >> 1) & 3;

  for (int c = 0; c < 32; ++c) {
    if (c + 2 < 32) stageW1(c + 2, (c + 2) % 3);

    {
      u16x4 bv0 = *(const u16x4*)&b1l[c * 32 + quad * 4];
      u16x4 bv1 = *(const u16x4*)&b1l[c * 32 + 16 + quad * 4];
      u16x4 o00, o01, o10, o11;
      #pragma unroll
      for (int r = 0; r < 4; r++) {
        o00[r] = f2b(gelu_fast(p00[r] + b2f(bv0[r])));
        o01[r] = f2b(gelu_fast(p01[r] + b2f(bv0[r])));
        o10[r] = f2b(gelu_fast(p10[r] + b2f(bv1[r])));
        o11[r] = f2b(gelu_fast(p11[r] + b2f(bv1[r])));
      }
      *(u16x4*)&tw[l16 * 40 + quad * 4]             = o00;
      *(u16x4*)&tw[(16 + l16) * 40 + quad * 4]      = o01;
      *(u16x4*)&tw[l16 * 40 + 16 + quad * 4]        = o10;
      *(u16x4*)&tw[(16 + l16) * 40 + 16 + quad * 4] = o11;
    }
    asm volatile("s_waitcnt lgkmcnt(0)" ::: "memory");
    __builtin_amdgcn_sched_barrier(0);

    {
      bf8 ta0, ta1;
      *(u16x8*)&ta0 = *(const u16x8*)&tw[l16 * 40 + quad * 8];
      *(u16x8*)&ta1 = *(const u16x8*)&tw[(16 + l16) * 40 + quad * 8];
      const unsigned short* w2b = (const unsigned short*)(smem + 49152 + (c & 1) * 16384);
      #pragma unroll
      for (int j = 0; j < 16; j++) {
        bf8 bw;
        *(u16x8*)&bw = *(const u16x8*)&w2b[(j * 16 + l16) * 32 + ((quad ^ gsw) * 8)];
        acc[0][j] = __builtin_amdgcn_mfma_f32_16x16x32_bf16(ta0, bw, acc[0][j], 0, 0, 0);
        acc[1][j] = __builtin_amdgcn_mfma_f32_16x16x32_bf16(ta1, bw, acc[1][j], 0, 0, 0);
      }
    }

    if (c + 2 < 32) asm volatile("s_waitcnt vmcnt(2)" ::: "memory");
    else            asm volatile("s_waitcnt vmcnt(0)" ::: "memory");
    __builtin_amdgcn_s_barrier();
    __builtin_amdgcn_sched_barrier(0);

    if (c + 2 < 32) stageW2(c + 2, (c + 2) & 1);
    if (c + 1 < 32) {
      const unsigned short* w1b = (const unsigned short*)(smem + ((c + 1) % 3) * 16384);
      p00 = {}; p01 = {}; p10 = {}; p11 = {};
      #pragma unroll
      for (int ks = 0; ks < 8; ks++) {
        const int slot = (ks * 4 + quad) ^ (l16 & 7);
        bf8 a0, a1;
        *(u16x8*)&a0 = *(const u16x8*)&w1b[l16 * 256 + slot * 8];
        *(u16x8*)&a1 = *(const u16x8*)&w1b[(16 + l16) * 256 + slot * 8];
        p00 = __builtin_amdgcn_mfma_f32_16x16x32_bf16(a0, areg[0][ks], p00, 0, 0, 0);
        p01 = __builtin_amdgcn_mfma_f32_16x16x32_bf16(a0, areg[1][ks], p01, 0, 0, 0);
        p10 = __builtin_amdgcn_mfma_f32_16x16x32_bf16(a1, areg[0][ks], p10, 0, 0, 0);
        p11 = __builtin_amdgcn_mfma_f32_16x16x32_bf16(a1, areg[1][ks], p11, 0, 0, 0);
      }
    }
  }

  if (!low) {
    if (tid == 0) {
      while (__hip_atomic_load(gate, __ATOMIC_ACQUIRE, __HIP_MEMORY_SCOPE_AGENT) < 128u)
        __builtin_amdgcn_s_sleep(32);
    }
    __syncthreads();
  }

  const bool obf = (*flagp) != 0;
  float* cf = (float*)smem;
  #pragma unroll
  for (int q = 0; q < 4; ++q) {
    __syncthreads();
    if ((wave >> 1) == q) {
      const int wl = (wave & 1) * 32;
      #pragma unroll
      for (int rg = 0; rg < 2; rg++)
        #pragma unroll
        for (int j = 0; j < 16; j++)
          #pragma unroll
          for (int r = 0; r < 4; r++)
            cf[(wl + rg * 16 + quad * 4 + r) * 260 + j * 16 + l16] = acc[rg][j][r];
    }
    __syncthreads();
    const unsigned short* hrow = hbase + (size_t)(q * 64) * 256;
    #pragma unroll
    for (int s = 0; s < 4; s++) {
      const int e = s * 4096 + tid * 8;
      const int row = e >> 8, col = e & 255;
      u16x8 rv = *(const u16x8*)&hrow[e];
      u16x8 b2v = *(const u16x8*)&bs2[col];
      float v[8];
      #pragma unroll
      for (int u = 0; u < 8; u++) v[u] = cf[row * 260 + col + u] + b2f(rv[u]) + b2f(b2v[u]);
      const size_t ob = (size_t)(grow + q * 64 + row) * 256 + col;
      if (obf) {
        u16x8 o;
        #pragma unroll
        for (int u = 0; u < 8; u++) o[u] = f2b(v[u]);
        *(u16x8*)&((unsigned short*)OUT)[ob] = o;
      } else {
        f32x4 oa, obv;
        oa[0]=v[0]; oa[1]=v[1]; oa[2]=v[2]; oa[3]=v[3];
        obv[0]=v[4]; obv[1]=v[5]; obv[2]=v[6]; obv[3]=v[7];
        *(f32x4*)&((float*)OUT)[ob] = oa;
        *(f32x4*)&((float*)OUT)[ob + 4] = obv;
      }
    }
  }

  if (low) {
    __syncthreads();
    if (tid == 0)
      __hip_atomic_fetch_add(gate, 1u, __ATOMIC_RELEASE, __HIP_MEMORY_SCOPE_AGENT);
  }
}

// ---------------------------------------------------------------------------
// accumG (E fused): per 256-token block k, thread (h,s):
//   e[t] = exp( dot(X[t, h*32..+32), Wk[s,:]) )   (E2d never materialized)
//   G[h,s,d] += e*X[t,h*32+d]; z += e.
// Xl reads are 2-address wave broadcasts (32 lanes same h) -> conflict-free.
// ---------------------------------------------------------------------------
__global__ __launch_bounds__(256) void accumG(
    const unsigned short* __restrict__ X,
    const unsigned short* __restrict__ wk,    // [32 s][32 d]
    float* __restrict__ Gp)                   // [256][8448]
{
  __shared__ float Xl[64 * 256];                         // 64 KB
  const int tid = threadIdx.x;
  const int k = blockIdx.x;
  const int h = tid >> 5, s = tid & 31;

  float wkr[32];
  #pragma unroll
  for (int d4 = 0; d4 < 4; d4++) {
    u16x8 wv = *(const u16x8*)&wk[s * 32 + d4 * 8];
    #pragma unroll
    for (int e = 0; e < 8; e++) wkr[d4 * 8 + e] = b2f(wv[e]);
  }

  float acc[32];
  #pragma unroll
  for (int d = 0; d < 32; d++) acc[d] = 0.f;
  float zacc = 0.f;

  for (int sub = 0; sub < 4; sub++) {
    const size_t r0s = (size_t)k * 256 + sub * 64;
    __syncthreads();
    #pragma unroll
    for (int i = 0; i < 8; i++) {
      const int flat = i * 2048 + tid * 8;
      u16x8 xv = *(const u16x8*)&X[r0s * 256 + flat];
      #pragma unroll
      for (int e = 0; e < 8; e++) Xl[flat + e] = b2f(xv[e]);
    }
    __syncthreads();

    for (int t = 0; t < 64; t++) {
      const int xb = t * 256 + h * 32;
      f32x4 xv[8];
      #pragma unroll
      for (int dq = 0; dq < 8; dq++) xv[dq] = *(const f32x4*)&Xl[xb + dq * 4];
      float dot = 0.f;
      #pragma unroll
      for (int dq = 0; dq < 8; dq++) {
        dot = fmaf(wkr[dq*4+0], xv[dq][0], dot);
        dot = fmaf(wkr[dq*4+1], xv[dq][1], dot);
        dot = fmaf(wkr[dq*4+2], xv[dq][2], dot);
        dot = fmaf(wkr[dq*4+3], xv[dq][3], dot);
      }
      const float e = __expf(dot);
      zacc += e;
      #pragma unroll
      for (int dq = 0; dq < 8; dq++) {
        acc[dq*4+0] = fmaf(e, xv[dq][0], acc[dq*4+0]);
        acc[dq*4+1] = fmaf(e, xv[dq][1], acc[dq*4+1]);
        acc[dq*4+2] = fmaf(e, xv[dq][2], acc[dq*4+2]);
        acc[dq*4+3] = fmaf(e, xv[dq][3], acc[dq*4+3]);
      }
    }
  }

  float* gp = &Gp[(size_t)k * 8448 + (size_t)tid * 32];
  #pragma unroll
  for (int dq = 0; dq < 8; dq++) {
    f32x4 o; o[0]=acc[dq*4]; o[1]=acc[dq*4+1]; o[2]=acc[dq*4+2]; o[3]=acc[dq*4+3];
    *(f32x4*)&gp[dq * 4] = o;
  }
  Gp[(size_t)k * 8448 + 8192 + tid] = zacc;
}

// Gfin[b][j] = sum_{i<32} Gp[b*32+i][j], b in 0..7.
__global__ __launch_bounds__(256) void reduceG(const float* __restrict__ Gp,
                                               float* __restrict__ Gfin) {
  const int o = blockIdx.x * 256 + threadIdx.x;
  if (o >= 67584) return;
  const int b = o / 8448;
  const int j = o - b * 8448;
  float s = 0.f;
  #pragma unroll 8
  for (int i = 0; i < 32; i++) s += Gp[(size_t)(b * 32 + i) * 8448 + j];
  Gfin[o] = s;
}

// kv_build (8 blocks): kvT[b][h][d][s] = (sum_dd G[h,s,dd]*Wv[d,dd]) / z[h,s].
__global__ __launch_bounds__(256) void kv_build(
    const float* __restrict__ Gfin, const unsigned short* __restrict__ Wv,
    unsigned short* __restrict__ KVT)
{
  __shared__ float Gl[8192];
  __shared__ float zl[256];
  __shared__ float wvt[1024];
  const int tid = threadIdx.x;
  const int b = blockIdx.x;
  for (int i = tid; i < 8192; i += 256) Gl[i] = Gfin[(size_t)b * 8448 + i];
  zl[tid] = Gfin[(size_t)b * 8448 + 8192 + tid];
  for (int i = tid; i < 1024; i += 256) {
    const int dd = i >> 5, d = i & 31;
    wvt[i] = b2f(Wv[d * 32 + dd]);
  }
  __syncthreads();

  const int h = tid >> 5, d = tid & 31;
  unsigned short row[32];
  for (int s = 0; s < 32; s++) {
    float a = 0.f;
    #pragma unroll
    for (int dd = 0; dd < 32; dd++) a += Gl[h * 1024 + s * 32 + dd] * wvt[dd * 32 + d];
    row[s] = f2b(a / zl[h * 32 + s]);
  }
  unsigned short* out = &KVT[(size_t)b * 8192 + (size_t)(h * 32 + d) * 32];
  #pragma unroll
  for (int e = 0; e < 4; e++) *(u16x8*)&out[e * 8] = *(u16x8*)&row[e * 8];
}

__global__ __launch_bounds__(256) void copy_h0(const unsigned short* __restrict__ src,
                                               unsigned short* __restrict__ dst) {
  size_t i = ((size_t)blockIdx.x * 256 + threadIdx.x) * 8;
  *(u16x8*)&dst[i] = *(const u16x8*)&src[i];
}

// ---------------------------------------------------------------------------
extern "C" void kernel_launch(void* const* d_in, const int* in_sizes, int n_in,
                              void* d_out, int out_size, void* d_ws, size_t ws_size,
                              hipStream_t stream)
{
  const void* fx   = d_in[0];
  const void* ln1w = d_in[1];
  const void* ln1b = d_in[2];
  const void* Wx   = d_in[3];
  const void* bx   = d_in[4];
  const void* Wq   = d_in[5];
  const void* Wk   = d_in[6];
  const void* Wv   = d_in[7];
  const void* Wo   = d_in[8];
  const void* bo   = d_in[9];
  const void* ln2w = d_in[10];
  const void* ln2b = d_in[11];
  const void* W1   = d_in[12];
  const void* b1   = d_in[13];
  const void* W2   = d_in[14];
  const void* b2   = d_in[15];

  // ws layout (~24.7 MB)
  unsigned short* ws    = (unsigned short*)d_ws;
  unsigned short* hid   = ws;                      // 16 MB: h-upper copy
  float* Gp             = (float*)ws;              // overlay: 256*8448 f32 (dead by MLP)
  unsigned short* wtab  = ws + 8388608;            // 661,248 u16
  unsigned short* h0res = wtab + 661248;           // 2,097,152 u16
  float* Gfin           = (float*)h0res;           // overlay: 67,584 f32
  unsigned short* kvT   = h0res + 2097152 + 131072;// 65,536 u16 (old KVB area)
  float* fpw = (float*)(kvT + 524288);
  float* mu1 = fpw;
  float* rs1 = fpw + 65536;
  float* mu2 = fpw + 131072;
  float* rs2 = fpw + 196608;
  int* flagp = (int*)(fpw + 262144);
  unsigned* gatep = (unsigned*)(flagp + 1);

  const int OFF_LN1W=0, OFF_LN1B=256, OFF_WX=512, OFF_BX=66048,
            OFF_WQ=66304, OFF_WK=67328, OFF_WV=68352,
            OFF_WO=69376, OFF_BO=134912, OFF_LN2W=135168, OFF_LN2B=135424,
            OFF_W1=135680, OFF_B1=397824, OFF_W2=398848, OFF_B2=660992;

  unsigned short* xm  = (unsigned short*)d_out;    // lower: xmid (dead after qkvwo)
  unsigned short* xup = xm + 16777216;             // upper: h

  // 0. dtype sniff + gate zero + weight table
  sniff_kernel<<<1, 64, 0, stream>>>((const unsigned*)fx, flagp, gatep);
  CvtDesc cd;
  const void* srcs[15] = {ln1w, ln1b, Wx, bx, Wq, Wk, Wv, Wo, bo, ln2w, ln2b, W1, b1, W2, b2};
  const int offs[15]   = {OFF_LN1W, OFF_LN1B, OFF_WX, OFF_BX, OFF_WQ, OFF_WK, OFF_WV,
                          OFF_WO, OFF_BO, OFF_LN2W, OFF_LN2B, OFF_W1, OFF_B1, OFF_W2, OFF_B2};
  const int ns[15]     = {256, 256, 65536, 256, 1024, 1024, 1024, 65536, 256, 256, 256,
                          262144, 1024, 262144, 256};
  for (int i = 0; i < 15; i++) { cd.src[i] = srcs[i]; cd.off[i] = offs[i]; cd.n[i] = ns[i]; }
  cvt_tab<<<dim3(1024, 15), 256, 0, stream>>>(cd, wtab, flagp);

  // 1. LN1 stats; xmid = LN1(fx) @ Wx^T + bx -> xm
  ln_stats<<<16384, 256, 0, stream>>>(fx, flagp, 1, mu1, rs1);
  gemm_bt_ln<<<dim3(512, 2), 256, 0, stream>>>(fx, flagp, 1, mu1, rs1,
      wtab + OFF_LN1W, wtab + OFF_LN1B, wtab + OFF_WX, wtab + OFF_BX,
      xm, 256, 256, 0);

  // 2. G partials (E fused in-register) + reduce; kvT compact
  accumG<<<256, 256, 0, stream>>>(xm, wtab + OFF_WK, Gp);
  reduceG<<<264, 256, 0, stream>>>(Gp, Gfin);
  kv_build<<<8, 256, 0, stream>>>(Gfin, wtab + OFF_WV, kvT);

  // 3. fused Qs/qkv/Wo: h = segsm(xmid@Wq^T)@kv@Wo^T + bo + fx -> xup
  qkvwo<<<512, 256, 0, stream>>>(xm, wtab + OFF_WQ, kvT, wtab + OFF_WO,
                                 wtab + OFF_BO, fx, flagp, xup);

  // 4. LN2 stats on h; copy h rows [32768,65536) -> ws hid area (Gp dead).
  ln_stats<<<16384, 256, 0, stream>>>(xup, flagp, 0, mu2, rs2);
  copy_h0<<<4096, 256, 0, stream>>>(xup + (size_t)32768 * 256, hid);

  // 5. fused MLP (R14, unchanged): single 256-block launch with parity gate.
  fused_mlp<<<256, 512, 0, stream>>>(xup, hid, mu2, rs2,
      wtab + OFF_LN2W, wtab + OFF_LN2B, wtab + OFF_W1, wtab + OFF_B1,
      wtab + OFF_W2, wtab + OFF_B2, d_out, flagp, gatep);
}